// Round 17
// baseline (294.184 us; speedup 1.0000x reference)
//
#include <hip/hip_runtime.h>
#include <stdint.h>

#define TT 4096    // B*S tokens
#define DD 1024    // model dim
#define EE 8       // experts
#define HH 1792    // hidden dim
#define MP 10240   // max padded gathered rows
#define MT128 80   // max 128-row tiles: ceil((8192+8*127)/128)=72, padded

typedef __attribute__((ext_vector_type(8))) short short8;    // 8 x bf16
typedef __attribute__((ext_vector_type(4))) short short4v;   // 4 x bf16
typedef __attribute__((ext_vector_type(4))) float f32x4;

static __device__ __forceinline__ unsigned short f2bf(float f) {
  union { float f; uint32_t u; } v; v.f = f;
  return (unsigned short)((v.u + 0x7fffu + ((v.u >> 16) & 1u)) >> 16);  // RNE
}
static __device__ __forceinline__ float bf2f(unsigned short h) {
  union { uint32_t u; float f; } v; v.u = ((uint32_t)h) << 16;
  return v.f;
}

// async global->LDS, 16B/lane; LDS dest wave-uniform, global SOURCE per-lane (m104)
static __device__ __forceinline__ void gll16(const void* g, const void* l) {
  __builtin_amdgcn_global_load_lds(
      (const __attribute__((address_space(1))) unsigned int*)g,
      (__attribute__((address_space(3))) unsigned int*)l, 16, 0, 0);
}

// ------------ prep (weights transpose+convert) + gate, ONE launch, 1 tile/block ------------
// r15 structure (92us; r16's wide-read regressed to 103 -> reverted). New this round:
// NON-TEMPORAL loads on the read-once f32 weights and NT stores on the write-once
// wguT/wdT outputs -- prep's ~300MB read-once/write-once footprint > 256MB L3, so
// normal write-allocate evicts the input stream (r14-r16: dur invariant to occupancy,
// VALU 10%, conflicts traced to gate path => cache-allocation is the remaining suspect).
// blocks [0,3584):      w_gate 64x64 tile -> wguT rows (h>>4)*32 + (h&15)
// blocks [3584,7168):   w_up   64x64 tile -> wguT rows (h>>4)*32 + 16 + (h&15)
// blocks [7168,10752):  w_down 64x64 tile -> wdT [D][H]
// blocks [10752,11776): gate, 4 tokens/block (bf16-emulated logits, top-2, probs, x->bf16)
__global__ __launch_bounds__(256) void prep_gate(
    const float* __restrict__ w_gate, const float* __restrict__ w_up,
    const float* __restrict__ w_down, unsigned short* __restrict__ wguT,
    unsigned short* __restrict__ wdT,
    const float* __restrict__ x, const float* __restrict__ gw,
    float2* __restrict__ wts, float* __restrict__ probs, int2* __restrict__ topk,
    unsigned short* __restrict__ xbf) {
  __shared__ float L0[64][65];
  const int tid = threadIdx.x;
  const int lr = tid >> 2, lc = (tid & 3) * 16;
  int bid = blockIdx.x;
  if (bid < 10752) {
    const int kind = bid / 3584;       // 0=gate, 1=up, 2=down
    const int rr = bid % 3584;
    const int e = rr / 448, r = rr % 448;
    if (kind < 2) {
      const int bx = r / 28, by = r % 28;  // bx: d-tile(16), by: h-tile(28)
      const float* src = (kind == 0 ? w_gate : w_up) +
                         (size_t)e * DD * HH + (size_t)lr * HH + (size_t)(bx * 64) * HH +
                         by * 64;
#pragma unroll
      for (int q = 0; q < 4; ++q) {
        const f32x4 v = __builtin_nontemporal_load((const f32x4*)(src + lc + 4 * q));
#pragma unroll
        for (int j = 0; j < 4; ++j) L0[lr][lc + 4 * q + j] = v[j];
      }
      __syncthreads();
      unsigned short b0[16];
#pragma unroll
      for (int q = 0; q < 16; ++q) b0[q] = f2bf(L0[lc + q][lr]);
      const int h = by * 64 + lr;                            // output logical row
      const int pg = (h >> 4) * 32 + kind * 16 + (h & 15);   // G/U interleave row
      unsigned short* dst = wguT + (size_t)e * 2 * HH * DD + (size_t)pg * DD +
                            (size_t)bx * 64 + lc;
      __builtin_nontemporal_store(*(const short8*)&b0[0], (short8*)dst);
      __builtin_nontemporal_store(*(const short8*)&b0[8], (short8*)(dst + 8));
    } else {
      const int bx = r / 16, by = r % 16;  // bx: h-tile(28), by: d-tile(16)
      const float* src = w_down + (size_t)e * HH * DD + (size_t)(bx * 64 + lr) * DD +
                         by * 64;
#pragma unroll
      for (int q = 0; q < 4; ++q) {
        const f32x4 v = __builtin_nontemporal_load((const f32x4*)(src + lc + 4 * q));
#pragma unroll
        for (int j = 0; j < 4; ++j) L0[lr][lc + 4 * q + j] = v[j];
      }
      __syncthreads();
      unsigned short b0[16];
#pragma unroll
      for (int q = 0; q < 16; ++q) b0[q] = f2bf(L0[lc + q][lr]);
      const int d = by * 64 + lr;
      unsigned short* dst = wdT + (size_t)e * DD * HH + (size_t)d * HH + bx * 64 + lc;
      __builtin_nontemporal_store(*(const short8*)&b0[0], (short8*)dst);
      __builtin_nontemporal_store(*(const short8*)&b0[8], (short8*)(dst + 8));
    }
  } else {
    // ---- gate path ----
    const int lane = tid & 63;
    const int wave = tid >> 6;
    const int t = (bid - 10752) * 4 + wave;
    const float* xr = x + (size_t)t * DD;
    float acc[EE];
#pragma unroll
    for (int e = 0; e < EE; ++e) acc[e] = 0.f;
#pragma unroll
    for (int i = 0; i < DD / 256; ++i) {
      const int d = (i * 64 + lane) * 4;
      const f32x4 xv = __builtin_nontemporal_load((const f32x4*)(xr + d));
      unsigned short us[4];
      float xb[4];
#pragma unroll
      for (int j = 0; j < 4; ++j) { us[j] = f2bf(xv[j]); xb[j] = bf2f(us[j]); }
      *(short4v*)(xbf + (size_t)t * DD + d) = *(const short4v*)us;  // folded x->bf16
#pragma unroll
      for (int e = 0; e < EE; ++e) {
        const f32x4 gv = *(const f32x4*)(gw + e * DD + d);
#pragma unroll
        for (int j = 0; j < 4; ++j) acc[e] += xb[j] * bf2f(f2bf(gv[j]));
      }
    }
#pragma unroll
    for (int e = 0; e < EE; ++e) {
#pragma unroll
      for (int off = 32; off > 0; off >>= 1)
        acc[e] += __shfl_xor(acc[e], off, 64);
    }
    if (lane == 0) {
      float lg[EE];
#pragma unroll
      for (int e = 0; e < EE; ++e) lg[e] = bf2f(f2bf(acc[e]));
      float m1 = -1e30f, m2 = -1e30f; int i1 = 0, i2 = 0;
#pragma unroll
      for (int e = 0; e < EE; ++e) {
        const float v = lg[e];
        if (v > m1) { m2 = m1; i2 = i1; m1 = v; i1 = e; }
        else if (v > m2) { m2 = v; i2 = e; }
      }
      const float e2 = expf(m2 - m1);
      const float w1 = 1.f / (1.f + e2);
      float p[EE]; float s = 0.f;
#pragma unroll
      for (int e = 0; e < EE; ++e) { p[e] = expf(lg[e] - m1); s += p[e]; }
      const float inv = 1.f / s;
#pragma unroll
      for (int e = 0; e < EE; ++e) probs[(size_t)t * EE + e] = p[e] * inv;
      wts[t] = make_float2(w1, e2 * w1);
      topk[t] = make_int2(i1, i2);
    }
  }
}

// ------- routing (pad to 128) + tile table + probs reduction + loss (one launch) -------
// wt_list sign encodes the combine slot: +w for topk[0]-match, -w for topk[1]-match.
__global__ __launch_bounds__(512) void route_kernel(
    const int2* __restrict__ topk, const float2* __restrict__ wts,
    const float* __restrict__ probs, int* __restrict__ tok_list,
    float* __restrict__ wt_list, int* __restrict__ tab128, float* __restrict__ tail) {
  const int lane = threadIdx.x & 63;
  const int e = threadIdx.x >> 6;  // one wave per expert
  __shared__ int cnts[EE], offs[EE];
  __shared__ float sm[EE];
  int cnt = 0;
  for (int i = 0; i < TT / 64; ++i) {
    const int2 k2 = topk[i * 64 + lane];
    cnt += __popcll(__ballot(k2.x == e || k2.y == e));
  }
  if (lane == 0) cnts[e] = cnt;
  __syncthreads();
  if (threadIdx.x == 0) {
    int off = 0, n128 = 0;
    for (int f = 0; f < EE; ++f) {
      offs[f] = off;
      const int pc = (cnts[f] + 127) & ~127;
      for (int j = 0; j < (pc >> 7); ++j) {
        tab128[2 * n128] = f; tab128[2 * n128 + 1] = off + 128 * j; ++n128;
      }
      off += pc;
    }
    for (; n128 < MT128; ++n128) { tab128[2 * n128] = -1; tab128[2 * n128 + 1] = 0; }
  }
  __syncthreads();
  int pos = offs[e];
  for (int i = 0; i < TT / 64; ++i) {
    const int t = i * 64 + lane;
    const int2 k2 = topk[t];
    const bool sel = (k2.x == e || k2.y == e);
    const unsigned long long m = __ballot(sel);
    if (sel) {
      const int p = pos + __popcll(m & ((1ull << lane) - 1ull));
      const float2 w2v = wts[t];
      tok_list[p] = t;
      wt_list[p] = (k2.x == e) ? w2v.x : -w2v.y;  // sign = combine slot
    }
    pos += __popcll(m);
  }
  const int pc = (cnt + 127) & ~127;  // pad slots: token 0, weight 0
  for (int s = cnt + lane; s < pc; s += 64) {
    tok_list[offs[e] + s] = 0;
    wt_list[offs[e] + s] = 0.f;
  }
  // probs reduction: wave e sums probs[:, e] (deterministic order)
  float racc = 0.f;
  for (int t = lane; t < TT; t += 64) racc += probs[(size_t)t * EE + e];
#pragma unroll
  for (int off = 32; off > 0; off >>= 1) racc += __shfl_xor(racc, off, 64);
  if (lane == 0) {
    const float m = racc * (1.f / TT);
    sm[e] = m;
    tail[1 + e] = m;
  }
  __syncthreads();
  if (threadIdx.x == 0) {
    float loss = 0.f;
#pragma unroll
    for (int f = 0; f < EE; ++f) loss += sm[f] * sm[f];
    tail[0] = (float)EE * loss;
  }
}

// ---------------- grouped GEMM body: m97 structure (verified r7/r9/r11) ----------------
// 128x128 tile, 4 waves, BK=64, single 32KB LDS, gll staging, (256,3) -- no spills.
// MODE 0: A = xbf rows GATHERED via tok_list; B=wguT; epilogue silu(g)*u -> act bf16.
//         nt-fastest grid (A-tile reuse across consecutive blocks).
// MODE 1: A=act, B=wdT; epilogue part[slot][tok] = bf16(y*|wt|), slot=sign(wt).
//         mt-fastest grid: with XCD-chunk swizzle, XCD k owns nt=k -> its 8 B-panels
//         (3.7MB) stay L2-resident; wdT fetched from HBM exactly once.
template <int MODE>
static __device__ __forceinline__ void gemm_body(
    const unsigned short* __restrict__ Ab, const unsigned short* __restrict__ Bb,
    const int* __restrict__ tab, const int* __restrict__ tok_list,
    const float* __restrict__ wt_list, unsigned short* __restrict__ dst) {
  constexpr int K   = (MODE == 0) ? DD : HH;     // 1024 / 1792
  constexpr int NBR = (MODE == 0) ? 2 * HH : DD; // B rows per expert
  constexpr int NNT = NBR / 128;                 // 28 / 8
  __shared__ unsigned short As[128 * 64];
  __shared__ unsigned short Bs[128 * 64];

  const int nwg = gridDim.x;  // %8==0 for both modes
  const int wgid = (blockIdx.x & 7) * (nwg >> 3) + (blockIdx.x >> 3);
  int mt, nt;
  if constexpr (MODE == 1) { mt = wgid % MT128; nt = wgid / MT128; }
  else                     { mt = wgid / NNT;   nt = wgid % NNT; }
  const int e = tab[2 * mt];
  if (e < 0) return;
  const int row0 = tab[2 * mt + 1];
  const int n0 = nt * 128;

  const int tid = threadIdx.x, lane = tid & 63, wave = tid >> 6;
  const int wm = (wave >> 1) * 64, wn = (wave & 1) * 64;
  const int fr = lane & 15, hi = lane >> 4;

  const unsigned short* Bt = Bb + ((size_t)e * NBR + n0) * K;

  // staging: pass q covers LDS bytes [q*4096, q*4096+4096), rows q*32+srow0
  const int srel = tid * 16;
  const int srow0 = srel >> 7;
  const int sch = (srel >> 4) & 7;

  // A source pointers (K-invariant): MODE 0 gathers through tok_list, MODE 1 linear
  const unsigned short* srcA[4];
#pragma unroll
  for (int q = 0; q < 4; ++q) {
    const int row = q * 32 + srow0;
    const int swz = (sch ^ (row & 7)) << 3;
    if constexpr (MODE == 0)
      srcA[q] = Ab + (size_t)tok_list[row0 + row] * DD + swz;
    else
      srcA[q] = Ab + (size_t)(row0 + row) * K + swz;
  }

  f32x4 acc[4][4];
#pragma unroll
  for (int i = 0; i < 4; ++i)
#pragma unroll
    for (int j = 0; j < 4; ++j) acc[i][j] = (f32x4){0.f, 0.f, 0.f, 0.f};

  for (int k0 = 0; k0 < K; k0 += 64) {
#pragma unroll
    for (int q = 0; q < 4; ++q)  // A tile: 16KB
      gll16(srcA[q] + k0, (const char*)As + q * 4096 + srel);
#pragma unroll
    for (int q = 0; q < 4; ++q) {  // B tile: 16KB
      const int row = q * 32 + srow0;
      gll16(Bt + (size_t)row * K + k0 + ((sch ^ (row & 7)) << 3),
            (const char*)Bs + q * 4096 + srel);
    }
    __syncthreads();  // compiler drains vmcnt+lgkmcnt
#pragma unroll
    for (int kc = 0; kc < 2; ++kc) {
      short8 a[4], b[4];
#pragma unroll
      for (int i = 0; i < 4; ++i) {
        const int row = wm + i * 16 + fr;
        a[i] = *(const short8*)((const char*)As + ((row * 128 + kc * 64 + hi * 16) ^ ((row & 7) << 4)));
      }
#pragma unroll
      for (int j = 0; j < 4; ++j) {
        const int row = wn + j * 16 + fr;
        b[j] = *(const short8*)((const char*)Bs + ((row * 128 + kc * 64 + hi * 16) ^ ((row & 7) << 4)));
      }
#pragma unroll
      for (int i = 0; i < 4; ++i)
#pragma unroll
        for (int j = 0; j < 4; ++j)
          acc[i][j] = __builtin_amdgcn_mfma_f32_16x16x32_bf16(a[i], b[j], acc[i][j], 0, 0, 0);
    }
    __syncthreads();
  }

  const int r4 = hi * 4;
  if constexpr (MODE == 0) {
#pragma unroll
    for (int i = 0; i < 4; ++i)
#pragma unroll
      for (int r = 0; r < 4; ++r) {
        const int row = row0 + wm + i * 16 + r4 + r;
#pragma unroll
        for (int jj = 0; jj < 2; ++jj) {
          const float g = acc[i][2 * jj][r], u = acc[i][2 * jj + 1][r];
          const int nb = n0 + wn + jj * 32;
          const int h = ((nb >> 5) << 4) + fr;   // de-interleave to real H col
          dst[(size_t)row * HH + h] = f2bf((g / (1.f + expf(-g))) * u);
        }
      }
  } else {
#pragma unroll
    for (int i = 0; i < 4; ++i)
#pragma unroll
      for (int r = 0; r < 4; ++r) {
        const int rl = row0 + wm + i * 16 + r4 + r;
        const int tok = tok_list[rl];
        const float ws = wt_list[rl];
        if (ws != 0.f) {  // pad rows (wt==0) skipped; real weights never exactly 0
          const int slot = (ws < 0.f) ? 1 : 0;
          const float wt = fabsf(ws);
          unsigned short* prow = dst + (size_t)slot * TT * DD + (size_t)tok * DD;
#pragma unroll
          for (int j = 0; j < 4; ++j)
            prow[n0 + wn + j * 16 + fr] = f2bf(acc[i][j][r] * wt);
        }
      }
  }
}

__global__ __launch_bounds__(256, 3) void gemm_gu(
    const unsigned short* __restrict__ Ab, const unsigned short* __restrict__ Bb,
    const int* __restrict__ tab, const int* __restrict__ tok_list,
    unsigned short* __restrict__ act) {
  gemm_body<0>(Ab, Bb, tab, tok_list, nullptr, act);
}

__global__ __launch_bounds__(256, 3) void gemm_dn(
    const unsigned short* __restrict__ Ab, const unsigned short* __restrict__ Bb,
    const int* __restrict__ tab, const int* __restrict__ tok_list,
    const float* __restrict__ wt_list, unsigned short* __restrict__ part) {
  gemm_body<1>(Ab, Bb, tab, tok_list, wt_list, part);
}

// ---------------- combine: out = part[0] + part[1] (bf16 -> f32), covers all TT*DD ------
__global__ __launch_bounds__(256) void combine_kernel(
    const unsigned short* __restrict__ part, float* __restrict__ out) {
  const size_t i = ((size_t)blockIdx.x * 256 + threadIdx.x) * 8;
  const short8 p0 = *(const short8*)(part + i);
  const short8 p1 = *(const short8*)(part + (size_t)TT * DD + i);
  f32x4 o0, o1;
#pragma unroll
  for (int j = 0; j < 4; ++j) {
    o0[j] = bf2f((unsigned short)p0[j]) + bf2f((unsigned short)p1[j]);
    o1[j] = bf2f((unsigned short)p0[4 + j]) + bf2f((unsigned short)p1[4 + j]);
  }
  *(f32x4*)(out + i) = o0;
  *(f32x4*)(out + i + 4) = o1;
}

extern "C" void kernel_launch(void* const* d_in, const int* in_sizes, int n_in,
                              void* d_out, int out_size, void* d_ws, size_t ws_size,
                              hipStream_t stream) {
  const float* x      = (const float*)d_in[0];
  const float* gw     = (const float*)d_in[1];
  const float* w_gate = (const float*)d_in[2];
  const float* w_up   = (const float*)d_in[3];
  const float* w_down = (const float*)d_in[4];
  float* out = (float*)d_out;
  float* tail = out + (size_t)TT * DD;  // [loss, mean_probs x 8]

  char* w = (char*)d_ws;
  size_t o = 0;
  auto carve = [&](size_t bytes) { char* p = w + o; o += (bytes + 255) & ~255ull; return p; };
  unsigned short* wguT = (unsigned short*)carve((size_t)EE * 2 * HH * DD * 2);  // interleaved G/U
  unsigned short* wdT  = (unsigned short*)carve((size_t)EE * DD * HH * 2);
  unsigned short* xbf  = (unsigned short*)carve((size_t)TT * DD * 2);           // bf16 x
  unsigned short* act  = (unsigned short*)carve((size_t)MP * HH * 2);
  float2* wts    = (float2*)carve((size_t)TT * 8);
  float* probs   = (float*)carve((size_t)TT * EE * 4);
  int2* topk     = (int2*)carve((size_t)TT * 8);
  int* tok_list  = (int*)carve((size_t)MP * 4);
  float* wt_list = (float*)carve((size_t)MP * 4);
  int* tab128    = (int*)carve((size_t)MT128 * 8);
  // part[2][TT][DD] bf16 (16.8 MB) aliases wguT (58.7 MB) -- wguT is dead after gemm_gu.
  unsigned short* part = wguT;

  prep_gate<<<11776, 256, 0, stream>>>(w_gate, w_up, w_down, wguT, wdT,
                                       x, gw, wts, probs, topk, xbf);
  route_kernel<<<1, 512, 0, stream>>>(topk, wts, probs, tok_list, wt_list, tab128, tail);

  gemm_gu<<<MT128 * 28, 256, 0, stream>>>(xbf, wguT, tab128, tok_list, act);
  gemm_dn<<<MT128 * 8, 256, 0, stream>>>(act, wdT, tab128, tok_list, wt_list, part);
  combine_kernel<<<TT * DD / 2048, 256, 0, stream>>>(part, out);
}

// Round 18
// 256.722 us; speedup vs baseline: 1.1459x; 1.1459x over previous
//
#include <hip/hip_runtime.h>
#include <stdint.h>

#define TT 4096    // B*S tokens
#define DD 1024    // model dim
#define EE 8       // experts
#define HH 1792    // hidden dim
#define MP 10240   // max padded gathered rows
#define MT128 80   // max 128-row tiles: ceil((8192+8*127)/128)=72, padded
#define GU_GRID (MT128 * 28)  // 2240, %8==0

typedef __attribute__((ext_vector_type(8))) short short8;    // 8 x bf16
typedef __attribute__((ext_vector_type(4))) short short4v;   // 4 x bf16
typedef __attribute__((ext_vector_type(4))) float f32x4;

static __device__ __forceinline__ unsigned short f2bf(float f) {
  union { float f; uint32_t u; } v; v.f = f;
  return (unsigned short)((v.u + 0x7fffu + ((v.u >> 16) & 1u)) >> 16);  // RNE
}
static __device__ __forceinline__ float bf2f(unsigned short h) {
  union { uint32_t u; float f; } v; v.u = ((uint32_t)h) << 16;
  return v.f;
}

// async global->LDS, 16B/lane; LDS dest wave-uniform, global SOURCE per-lane (m104)
static __device__ __forceinline__ void gll16(const void* g, const void* l) {
  __builtin_amdgcn_global_load_lds(
      (const __attribute__((address_space(1))) unsigned int*)g,
      (__attribute__((address_space(3))) unsigned int*)l, 16, 0, 0);
}

// ---- one 64x64 transpose+convert tile for w_gate/w_up -> wguT (G/U interleave) ----
static __device__ __forceinline__ void prep_gu_tile(
    float (*L0)[65], int kind, int rr, const float* __restrict__ w_gate,
    const float* __restrict__ w_up, unsigned short* __restrict__ wguT, int tid) {
  const int lr = tid >> 2, lc = (tid & 3) * 16;
  const int e = rr / 448, r = rr % 448;
  const int bx = r / 28, by = r % 28;  // bx: d-tile(16), by: h-tile(28)
  const float* src = (kind == 0 ? w_gate : w_up) +
                     (size_t)e * DD * HH + (size_t)(bx * 64 + lr) * HH + by * 64;
#pragma unroll
  for (int q = 0; q < 4; ++q) {
    const f32x4 v = *(const f32x4*)(src + lc + 4 * q);
#pragma unroll
    for (int j = 0; j < 4; ++j) L0[lr][lc + 4 * q + j] = v[j];  // L0[d_local][h_local]
  }
  __syncthreads();
  unsigned short b0[16];
#pragma unroll
  for (int q = 0; q < 16; ++q) b0[q] = f2bf(L0[lc + q][lr]);    // (d=lc+q, h=lr)
  const int h = by * 64 + lr;                            // output logical row
  const int pg = (h >> 4) * 32 + kind * 16 + (h & 15);   // G/U interleave row
  unsigned short* dst = wguT + (size_t)e * 2 * HH * DD + (size_t)pg * DD +
                        (size_t)bx * 64 + lc;
  *(short8*)(dst) = *(const short8*)&b0[0];
  *(short8*)(dst + 8) = *(const short8*)&b0[8];
}

// ---- one 64x64 transpose+convert tile for w_down -> wdT [D][H] ----
static __device__ __forceinline__ void prep_dn_tile(
    float (*L0)[65], int rr, const float* __restrict__ w_down,
    unsigned short* __restrict__ wdT, int tid) {
  const int lr = tid >> 2, lc = (tid & 3) * 16;
  const int e = rr / 448, r = rr % 448;
  const int bx = r / 16, by = r % 16;  // bx: h-tile(28), by: d-tile(16)
  const float* src = w_down + (size_t)e * HH * DD + (size_t)(bx * 64 + lr) * DD + by * 64;
#pragma unroll
  for (int q = 0; q < 4; ++q) {
    const f32x4 v = *(const f32x4*)(src + lc + 4 * q);
#pragma unroll
    for (int j = 0; j < 4; ++j) L0[lr][lc + 4 * q + j] = v[j];  // L0[h_local][d_local]
  }
  __syncthreads();
  unsigned short b0[16];
#pragma unroll
  for (int q = 0; q < 16; ++q) b0[q] = f2bf(L0[lc + q][lr]);    // (h=lc+q, d=lr)
  const int d = by * 64 + lr;
  unsigned short* dst = wdT + (size_t)e * DD * HH + (size_t)d * HH + bx * 64 + lc;
  *(short8*)(dst) = *(const short8*)&b0[0];
  *(short8*)(dst + 8) = *(const short8*)&b0[8];
}

// ------------ kernel A: gate/up weight tiles + gate path, ONE launch ------------
// blocks [0,3584): w_gate tiles; [3584,7168): w_up tiles; [7168,8192): gate 4 tok/block
__global__ __launch_bounds__(256) void prep_gu_gate(
    const float* __restrict__ w_gate, const float* __restrict__ w_up,
    unsigned short* __restrict__ wguT,
    const float* __restrict__ x, const float* __restrict__ gw,
    float2* __restrict__ wts, float* __restrict__ probs, int2* __restrict__ topk,
    unsigned short* __restrict__ xbf) {
  __shared__ float L0[64][65];
  const int tid = threadIdx.x;
  const int bid = blockIdx.x;
  if (bid < 7168) {
    prep_gu_tile(L0, bid / 3584, bid % 3584, w_gate, w_up, wguT, tid);
  } else {
    // ---- gate path ----
    const int lane = tid & 63;
    const int wave = tid >> 6;
    const int t = (bid - 7168) * 4 + wave;
    const float* xr = x + (size_t)t * DD;
    float acc[EE];
#pragma unroll
    for (int e = 0; e < EE; ++e) acc[e] = 0.f;
#pragma unroll
    for (int i = 0; i < DD / 256; ++i) {
      const int d = (i * 64 + lane) * 4;
      const f32x4 xv = *(const f32x4*)(xr + d);
      unsigned short us[4];
      float xb[4];
#pragma unroll
      for (int j = 0; j < 4; ++j) { us[j] = f2bf(xv[j]); xb[j] = bf2f(us[j]); }
      *(short4v*)(xbf + (size_t)t * DD + d) = *(const short4v*)us;  // folded x->bf16
#pragma unroll
      for (int e = 0; e < EE; ++e) {
        const f32x4 gv = *(const f32x4*)(gw + e * DD + d);
#pragma unroll
        for (int j = 0; j < 4; ++j) acc[e] += xb[j] * bf2f(f2bf(gv[j]));
      }
    }
#pragma unroll
    for (int e = 0; e < EE; ++e) {
#pragma unroll
      for (int off = 32; off > 0; off >>= 1)
        acc[e] += __shfl_xor(acc[e], off, 64);
    }
    if (lane == 0) {
      float lg[EE];
#pragma unroll
      for (int e = 0; e < EE; ++e) lg[e] = bf2f(f2bf(acc[e]));
      float m1 = -1e30f, m2 = -1e30f; int i1 = 0, i2 = 0;
#pragma unroll
      for (int e = 0; e < EE; ++e) {
        const float v = lg[e];
        if (v > m1) { m2 = m1; i2 = i1; m1 = v; i1 = e; }
        else if (v > m2) { m2 = v; i2 = e; }
      }
      const float e2 = expf(m2 - m1);
      const float w1 = 1.f / (1.f + e2);
      float p[EE]; float s = 0.f;
#pragma unroll
      for (int e = 0; e < EE; ++e) { p[e] = expf(lg[e] - m1); s += p[e]; }
      const float inv = 1.f / s;
#pragma unroll
      for (int e = 0; e < EE; ++e) probs[(size_t)t * EE + e] = p[e] * inv;
      wts[t] = make_float2(w1, e2 * w1);
      topk[t] = make_int2(i1, i2);
    }
  }
}

// ------- routing (pad to 128) + tile table + probs reduction + loss (one launch) -------
// wt_list sign encodes the combine slot: +w for topk[0]-match, -w for topk[1]-match.
__global__ __launch_bounds__(512) void route_kernel(
    const int2* __restrict__ topk, const float2* __restrict__ wts,
    const float* __restrict__ probs, int* __restrict__ tok_list,
    float* __restrict__ wt_list, int* __restrict__ tab128, float* __restrict__ tail) {
  const int lane = threadIdx.x & 63;
  const int e = threadIdx.x >> 6;  // one wave per expert
  __shared__ int cnts[EE], offs[EE];
  __shared__ float sm[EE];
  int cnt = 0;
  for (int i = 0; i < TT / 64; ++i) {
    const int2 k2 = topk[i * 64 + lane];
    cnt += __popcll(__ballot(k2.x == e || k2.y == e));
  }
  if (lane == 0) cnts[e] = cnt;
  __syncthreads();
  if (threadIdx.x == 0) {
    int off = 0, n128 = 0;
    for (int f = 0; f < EE; ++f) {
      offs[f] = off;
      const int pc = (cnts[f] + 127) & ~127;
      for (int j = 0; j < (pc >> 7); ++j) {
        tab128[2 * n128] = f; tab128[2 * n128 + 1] = off + 128 * j; ++n128;
      }
      off += pc;
    }
    for (; n128 < MT128; ++n128) { tab128[2 * n128] = -1; tab128[2 * n128 + 1] = 0; }
  }
  __syncthreads();
  int pos = offs[e];
  for (int i = 0; i < TT / 64; ++i) {
    const int t = i * 64 + lane;
    const int2 k2 = topk[t];
    const bool sel = (k2.x == e || k2.y == e);
    const unsigned long long m = __ballot(sel);
    if (sel) {
      const int p = pos + __popcll(m & ((1ull << lane) - 1ull));
      const float2 w2v = wts[t];
      tok_list[p] = t;
      wt_list[p] = (k2.x == e) ? w2v.x : -w2v.y;  // sign = combine slot
    }
    pos += __popcll(m);
  }
  const int pc = (cnt + 127) & ~127;  // pad slots: token 0, weight 0
  for (int s = cnt + lane; s < pc; s += 64) {
    tok_list[offs[e] + s] = 0;
    wt_list[offs[e] + s] = 0.f;
  }
  // probs reduction: wave e sums probs[:, e] (deterministic order)
  float racc = 0.f;
  for (int t = lane; t < TT; t += 64) racc += probs[(size_t)t * EE + e];
#pragma unroll
  for (int off = 32; off > 0; off >>= 1) racc += __shfl_xor(racc, off, 64);
  if (lane == 0) {
    const float m = racc * (1.f / TT);
    sm[e] = m;
    tail[1 + e] = m;
  }
  __syncthreads();
  if (threadIdx.x == 0) {
    float loss = 0.f;
#pragma unroll
    for (int f = 0; f < EE; ++f) loss += sm[f] * sm[f];
    tail[0] = (float)EE * loss;
  }
}

// ---------------- grouped GEMM body: m97 structure (verified r7/r9/r11) ----------------
// 128x128 tile, 4 waves, BK=64, single 32KB LDS (caller-provided), gll staging.
// MODE 0: A = xbf rows GATHERED via tok_list; B=wguT; epilogue silu(g)*u -> act bf16.
//         nt-fastest grid (A-tile reuse); bid/nwg passed explicitly (merged launch).
// MODE 1: A=act, B=wdT; epilogue part[slot][tok] = bf16(y*|wt|), slot=sign(wt).
//         mt-fastest grid: XCD k owns nt=k -> its 8 B-panels (3.7MB) L2-resident.
template <int MODE>
static __device__ __forceinline__ void gemm_body(
    unsigned short* As, unsigned short* Bs, int bid, int nwg,
    const unsigned short* __restrict__ Ab, const unsigned short* __restrict__ Bb,
    const int* __restrict__ tab, const int* __restrict__ tok_list,
    const float* __restrict__ wt_list, unsigned short* __restrict__ dst) {
  constexpr int K   = (MODE == 0) ? DD : HH;     // 1024 / 1792
  constexpr int NBR = (MODE == 0) ? 2 * HH : DD; // B rows per expert
  constexpr int NNT = NBR / 128;                 // 28 / 8

  const int wgid = (bid & 7) * (nwg >> 3) + (bid >> 3);  // XCD-chunk swizzle
  int mt, nt;
  if constexpr (MODE == 1) { mt = wgid % MT128; nt = wgid / MT128; }
  else                     { mt = wgid / NNT;   nt = wgid % NNT; }
  const int e = tab[2 * mt];
  if (e < 0) return;
  const int row0 = tab[2 * mt + 1];
  const int n0 = nt * 128;

  const int tid = threadIdx.x, lane = tid & 63, wave = tid >> 6;
  const int wm = (wave >> 1) * 64, wn = (wave & 1) * 64;
  const int fr = lane & 15, hi = lane >> 4;

  const unsigned short* Bt = Bb + ((size_t)e * NBR + n0) * K;

  // staging: pass q covers LDS bytes [q*4096, q*4096+4096), rows q*32+srow0
  const int srel = tid * 16;
  const int srow0 = srel >> 7;
  const int sch = (srel >> 4) & 7;

  // A source pointers (K-invariant): MODE 0 gathers through tok_list, MODE 1 linear
  const unsigned short* srcA[4];
#pragma unroll
  for (int q = 0; q < 4; ++q) {
    const int row = q * 32 + srow0;
    const int swz = (sch ^ (row & 7)) << 3;
    if constexpr (MODE == 0)
      srcA[q] = Ab + (size_t)tok_list[row0 + row] * DD + swz;
    else
      srcA[q] = Ab + (size_t)(row0 + row) * K + swz;
  }

  f32x4 acc[4][4];
#pragma unroll
  for (int i = 0; i < 4; ++i)
#pragma unroll
    for (int j = 0; j < 4; ++j) acc[i][j] = (f32x4){0.f, 0.f, 0.f, 0.f};

  for (int k0 = 0; k0 < K; k0 += 64) {
#pragma unroll
    for (int q = 0; q < 4; ++q)  // A tile: 16KB
      gll16(srcA[q] + k0, (const char*)As + q * 4096 + srel);
#pragma unroll
    for (int q = 0; q < 4; ++q) {  // B tile: 16KB
      const int row = q * 32 + srow0;
      gll16(Bt + (size_t)row * K + k0 + ((sch ^ (row & 7)) << 3),
            (const char*)Bs + q * 4096 + srel);
    }
    __syncthreads();  // compiler drains vmcnt+lgkmcnt
#pragma unroll
    for (int kc = 0; kc < 2; ++kc) {
      short8 a[4], b[4];
#pragma unroll
      for (int i = 0; i < 4; ++i) {
        const int row = wm + i * 16 + fr;
        a[i] = *(const short8*)((const char*)As + ((row * 128 + kc * 64 + hi * 16) ^ ((row & 7) << 4)));
      }
#pragma unroll
      for (int j = 0; j < 4; ++j) {
        const int row = wn + j * 16 + fr;
        b[j] = *(const short8*)((const char*)Bs + ((row * 128 + kc * 64 + hi * 16) ^ ((row & 7) << 4)));
      }
#pragma unroll
      for (int i = 0; i < 4; ++i)
#pragma unroll
        for (int j = 0; j < 4; ++j)
          acc[i][j] = __builtin_amdgcn_mfma_f32_16x16x32_bf16(a[i], b[j], acc[i][j], 0, 0, 0);
    }
    __syncthreads();
  }

  const int r4 = hi * 4;
  if constexpr (MODE == 0) {
#pragma unroll
    for (int i = 0; i < 4; ++i)
#pragma unroll
      for (int r = 0; r < 4; ++r) {
        const int row = row0 + wm + i * 16 + r4 + r;
#pragma unroll
        for (int jj = 0; jj < 2; ++jj) {
          const float g = acc[i][2 * jj][r], u = acc[i][2 * jj + 1][r];
          const int nb = n0 + wn + jj * 32;
          const int h = ((nb >> 5) << 4) + fr;   // de-interleave to real H col
          dst[(size_t)row * HH + h] = f2bf((g / (1.f + expf(-g))) * u);
        }
      }
  } else {
#pragma unroll
    for (int i = 0; i < 4; ++i)
#pragma unroll
      for (int r = 0; r < 4; ++r) {
        const int rl = row0 + wm + i * 16 + r4 + r;
        const int tok = tok_list[rl];
        const float ws = wt_list[rl];
        if (ws != 0.f) {  // pad rows (wt==0) skipped; real weights never exactly 0
          const int slot = (ws < 0.f) ? 1 : 0;
          const float wt = fabsf(ws);
          unsigned short* prow = dst + (size_t)slot * TT * DD + (size_t)tok * DD;
#pragma unroll
          for (int j = 0; j < 4; ++j)
            prow[n0 + wn + j * 16 + fr] = f2bf(acc[i][j][r] * wt);
        }
      }
  }
}

// ------------ kernel B: gemm_gu (blocks 0..2239) + w_down prep tiles (2240..5823) ------------
// gemm_gu is compute/barrier-bound (1.6/6.3 TB/s, MfmaUtil 28%); the memory-only prep
// tiles fill spare CU slots + bandwidth (m114 co-schedule). wdT not read until gemm_dn.
__global__ __launch_bounds__(256, 3) void gemm_gu_pd(
    const unsigned short* __restrict__ Ab, const unsigned short* __restrict__ Bb,
    const int* __restrict__ tab, const int* __restrict__ tok_list,
    unsigned short* __restrict__ act,
    const float* __restrict__ w_down, unsigned short* __restrict__ wdT) {
  __shared__ char smem[32768] __attribute__((aligned(16)));
  const int bid = blockIdx.x;
  if (bid < GU_GRID) {
    gemm_body<0>((unsigned short*)smem, (unsigned short*)(smem + 16384),
                 bid, GU_GRID, Ab, Bb, tab, tok_list, nullptr, act);
  } else {
    prep_dn_tile((float(*)[65])smem, bid - GU_GRID, w_down, wdT, threadIdx.x);
  }
}

__global__ __launch_bounds__(256, 3) void gemm_dn(
    const unsigned short* __restrict__ Ab, const unsigned short* __restrict__ Bb,
    const int* __restrict__ tab, const int* __restrict__ tok_list,
    const float* __restrict__ wt_list, unsigned short* __restrict__ part) {
  __shared__ char smem[32768] __attribute__((aligned(16)));
  gemm_body<1>((unsigned short*)smem, (unsigned short*)(smem + 16384),
               blockIdx.x, gridDim.x, Ab, Bb, tab, tok_list, wt_list, part);
}

// ---------------- combine: out = part[0] + part[1] (bf16 -> f32), covers all TT*DD ------
__global__ __launch_bounds__(256) void combine_kernel(
    const unsigned short* __restrict__ part, float* __restrict__ out) {
  const size_t i = ((size_t)blockIdx.x * 256 + threadIdx.x) * 8;
  const short8 p0 = *(const short8*)(part + i);
  const short8 p1 = *(const short8*)(part + (size_t)TT * DD + i);
  f32x4 o0, o1;
#pragma unroll
  for (int j = 0; j < 4; ++j) {
    o0[j] = bf2f((unsigned short)p0[j]) + bf2f((unsigned short)p1[j]);
    o1[j] = bf2f((unsigned short)p0[4 + j]) + bf2f((unsigned short)p1[4 + j]);
  }
  *(f32x4*)(out + i) = o0;
  *(f32x4*)(out + i + 4) = o1;
}

extern "C" void kernel_launch(void* const* d_in, const int* in_sizes, int n_in,
                              void* d_out, int out_size, void* d_ws, size_t ws_size,
                              hipStream_t stream) {
  const float* x      = (const float*)d_in[0];
  const float* gw     = (const float*)d_in[1];
  const float* w_gate = (const float*)d_in[2];
  const float* w_up   = (const float*)d_in[3];
  const float* w_down = (const float*)d_in[4];
  float* out = (float*)d_out;
  float* tail = out + (size_t)TT * DD;  // [loss, mean_probs x 8]

  char* w = (char*)d_ws;
  size_t o = 0;
  auto carve = [&](size_t bytes) { char* p = w + o; o += (bytes + 255) & ~255ull; return p; };
  unsigned short* wguT = (unsigned short*)carve((size_t)EE * 2 * HH * DD * 2);  // interleaved G/U
  unsigned short* wdT  = (unsigned short*)carve((size_t)EE * DD * HH * 2);
  unsigned short* xbf  = (unsigned short*)carve((size_t)TT * DD * 2);           // bf16 x
  unsigned short* act  = (unsigned short*)carve((size_t)MP * HH * 2);
  float2* wts    = (float2*)carve((size_t)TT * 8);
  float* probs   = (float*)carve((size_t)TT * EE * 4);
  int2* topk     = (int2*)carve((size_t)TT * 8);
  int* tok_list  = (int*)carve((size_t)MP * 4);
  float* wt_list = (float*)carve((size_t)MP * 4);
  int* tab128    = (int*)carve((size_t)MT128 * 8);
  // part[2][TT][DD] bf16 (16.8 MB) aliases wguT (58.7 MB) -- wguT is dead after gemm_gu.
  unsigned short* part = wguT;

  prep_gu_gate<<<8192, 256, 0, stream>>>(w_gate, w_up, wguT, x, gw, wts, probs, topk, xbf);
  route_kernel<<<1, 512, 0, stream>>>(topk, wts, probs, tok_list, wt_list, tab128, tail);

  gemm_gu_pd<<<GU_GRID + 3584, 256, 0, stream>>>(xbf, wguT, tab128, tok_list, act,
                                                 w_down, wdT);
  gemm_dn<<<MT128 * 8, 256, 0, stream>>>(act, wdT, tab128, tok_list, wt_list, part);
  combine_kernel<<<TT * DD / 2048, 256, 0, stream>>>(part, out);
}

// Round 19
// 251.680 us; speedup vs baseline: 1.1689x; 1.0200x over previous
//
#include <hip/hip_runtime.h>
#include <stdint.h>

#define TT 4096    // B*S tokens
#define DD 1024    // model dim
#define EE 8       // experts
#define HH 1792    // hidden dim
#define MP 10240   // max padded gathered rows
#define MT128 80   // max 128-row tiles: ceil((8192+8*127)/128)=72, padded
#define GU_GRID (MT128 * 28)  // 2240, %8==0

typedef __attribute__((ext_vector_type(8))) short short8;    // 8 x bf16
typedef __attribute__((ext_vector_type(4))) short short4v;   // 4 x bf16
typedef __attribute__((ext_vector_type(4))) float f32x4;

static __device__ __forceinline__ unsigned short f2bf(float f) {
  union { float f; uint32_t u; } v; v.f = f;
  return (unsigned short)((v.u + 0x7fffu + ((v.u >> 16) & 1u)) >> 16);  // RNE
}
static __device__ __forceinline__ float bf2f(unsigned short h) {
  union { uint32_t u; float f; } v; v.u = ((uint32_t)h) << 16;
  return v.f;
}

// async global->LDS, 16B/lane; LDS dest wave-uniform, global SOURCE per-lane (m104)
static __device__ __forceinline__ void gll16(const void* g, const void* l) {
  __builtin_amdgcn_global_load_lds(
      (const __attribute__((address_space(1))) unsigned int*)g,
      (__attribute__((address_space(3))) unsigned int*)l, 16, 0, 0);
}

// ---- one 64x64 transpose+convert tile for w_gate/w_up -> wguT (G/U interleave) ----
static __device__ __forceinline__ void prep_gu_tile(
    float (*L0)[65], int kind, int rr, const float* __restrict__ w_gate,
    const float* __restrict__ w_up, unsigned short* __restrict__ wguT, int tid) {
  const int lr = tid >> 2, lc = (tid & 3) * 16;
  const int e = rr / 448, r = rr % 448;
  const int bx = r / 28, by = r % 28;  // bx: d-tile(16), by: h-tile(28)
  const float* src = (kind == 0 ? w_gate : w_up) +
                     (size_t)e * DD * HH + (size_t)(bx * 64 + lr) * HH + by * 64;
#pragma unroll
  for (int q = 0; q < 4; ++q) {
    const f32x4 v = *(const f32x4*)(src + lc + 4 * q);
#pragma unroll
    for (int j = 0; j < 4; ++j) L0[lr][lc + 4 * q + j] = v[j];  // L0[d_local][h_local]
  }
  __syncthreads();
  unsigned short b0[16];
#pragma unroll
  for (int q = 0; q < 16; ++q) b0[q] = f2bf(L0[lc + q][lr]);    // (d=lc+q, h=lr)
  const int h = by * 64 + lr;                            // output logical row
  const int pg = (h >> 4) * 32 + kind * 16 + (h & 15);   // G/U interleave row
  unsigned short* dst = wguT + (size_t)e * 2 * HH * DD + (size_t)pg * DD +
                        (size_t)bx * 64 + lc;
  *(short8*)(dst) = *(const short8*)&b0[0];
  *(short8*)(dst + 8) = *(const short8*)&b0[8];
}

// ---- one 64x64 transpose+convert tile for w_down -> wdT [D][H] ----
static __device__ __forceinline__ void prep_dn_tile(
    float (*L0)[65], int rr, const float* __restrict__ w_down,
    unsigned short* __restrict__ wdT, int tid) {
  const int lr = tid >> 2, lc = (tid & 3) * 16;
  const int e = rr / 448, r = rr % 448;
  const int bx = r / 16, by = r % 16;  // bx: h-tile(28), by: d-tile(16)
  const float* src = w_down + (size_t)e * HH * DD + (size_t)(bx * 64 + lr) * DD + by * 64;
#pragma unroll
  for (int q = 0; q < 4; ++q) {
    const f32x4 v = *(const f32x4*)(src + lc + 4 * q);
#pragma unroll
    for (int j = 0; j < 4; ++j) L0[lr][lc + 4 * q + j] = v[j];  // L0[h_local][d_local]
  }
  __syncthreads();
  unsigned short b0[16];
#pragma unroll
  for (int q = 0; q < 16; ++q) b0[q] = f2bf(L0[lc + q][lr]);    // (h=lc+q, d=lr)
  const int d = by * 64 + lr;
  unsigned short* dst = wdT + (size_t)e * DD * HH + (size_t)d * HH + bx * 64 + lc;
  *(short8*)(dst) = *(const short8*)&b0[0];
  *(short8*)(dst + 8) = *(const short8*)&b0[8];
}

// ------------ kernel A: gate/up weight tiles + gate path, ONE launch ------------
// blocks [0,3584): w_gate tiles; [3584,7168): w_up tiles; [7168,8192): gate 4 tok/block
__global__ __launch_bounds__(256) void prep_gu_gate(
    const float* __restrict__ w_gate, const float* __restrict__ w_up,
    unsigned short* __restrict__ wguT,
    const float* __restrict__ x, const float* __restrict__ gw,
    float2* __restrict__ wts, float* __restrict__ probs, int2* __restrict__ topk,
    unsigned short* __restrict__ xbf) {
  __shared__ float L0[64][65];
  const int tid = threadIdx.x;
  const int bid = blockIdx.x;
  if (bid < 7168) {
    prep_gu_tile(L0, bid / 3584, bid % 3584, w_gate, w_up, wguT, tid);
  } else {
    // ---- gate path ----
    const int lane = tid & 63;
    const int wave = tid >> 6;
    const int t = (bid - 7168) * 4 + wave;
    const float* xr = x + (size_t)t * DD;
    float acc[EE];
#pragma unroll
    for (int e = 0; e < EE; ++e) acc[e] = 0.f;
#pragma unroll
    for (int i = 0; i < DD / 256; ++i) {
      const int d = (i * 64 + lane) * 4;
      const f32x4 xv = *(const f32x4*)(xr + d);
      unsigned short us[4];
      float xb[4];
#pragma unroll
      for (int j = 0; j < 4; ++j) { us[j] = f2bf(xv[j]); xb[j] = bf2f(us[j]); }
      *(short4v*)(xbf + (size_t)t * DD + d) = *(const short4v*)us;  // folded x->bf16
#pragma unroll
      for (int e = 0; e < EE; ++e) {
        const f32x4 gv = *(const f32x4*)(gw + e * DD + d);
#pragma unroll
        for (int j = 0; j < 4; ++j) acc[e] += xb[j] * bf2f(f2bf(gv[j]));
      }
    }
#pragma unroll
    for (int e = 0; e < EE; ++e) {
#pragma unroll
      for (int off = 32; off > 0; off >>= 1)
        acc[e] += __shfl_xor(acc[e], off, 64);
    }
    if (lane == 0) {
      float lg[EE];
#pragma unroll
      for (int e = 0; e < EE; ++e) lg[e] = bf2f(f2bf(acc[e]));
      float m1 = -1e30f, m2 = -1e30f; int i1 = 0, i2 = 0;
#pragma unroll
      for (int e = 0; e < EE; ++e) {
        const float v = lg[e];
        if (v > m1) { m2 = m1; i2 = i1; m1 = v; i1 = e; }
        else if (v > m2) { m2 = v; i2 = e; }
      }
      const float e2 = expf(m2 - m1);
      const float w1 = 1.f / (1.f + e2);
      float p[EE]; float s = 0.f;
#pragma unroll
      for (int e = 0; e < EE; ++e) { p[e] = expf(lg[e] - m1); s += p[e]; }
      const float inv = 1.f / s;
#pragma unroll
      for (int e = 0; e < EE; ++e) probs[(size_t)t * EE + e] = p[e] * inv;
      wts[t] = make_float2(w1, e2 * w1);
      topk[t] = make_int2(i1, i2);
    }
  }
}

// ------- routing (pad to 128) + tile table + probs reduction + loss (one launch) -------
// wt_list sign encodes the combine slot: +w for topk[0]-match, -w for topk[1]-match.
__global__ __launch_bounds__(512) void route_kernel(
    const int2* __restrict__ topk, const float2* __restrict__ wts,
    const float* __restrict__ probs, int* __restrict__ tok_list,
    float* __restrict__ wt_list, int* __restrict__ tab128, float* __restrict__ tail) {
  const int lane = threadIdx.x & 63;
  const int e = threadIdx.x >> 6;  // one wave per expert
  __shared__ int cnts[EE], offs[EE];
  __shared__ float sm[EE];
  int cnt = 0;
  for (int i = 0; i < TT / 64; ++i) {
    const int2 k2 = topk[i * 64 + lane];
    cnt += __popcll(__ballot(k2.x == e || k2.y == e));
  }
  if (lane == 0) cnts[e] = cnt;
  __syncthreads();
  if (threadIdx.x == 0) {
    int off = 0, n128 = 0;
    for (int f = 0; f < EE; ++f) {
      offs[f] = off;
      const int pc = (cnts[f] + 127) & ~127;
      for (int j = 0; j < (pc >> 7); ++j) {
        tab128[2 * n128] = f; tab128[2 * n128 + 1] = off + 128 * j; ++n128;
      }
      off += pc;
    }
    for (; n128 < MT128; ++n128) { tab128[2 * n128] = -1; tab128[2 * n128 + 1] = 0; }
  }
  __syncthreads();
  int pos = offs[e];
  for (int i = 0; i < TT / 64; ++i) {
    const int t = i * 64 + lane;
    const int2 k2 = topk[t];
    const bool sel = (k2.x == e || k2.y == e);
    const unsigned long long m = __ballot(sel);
    if (sel) {
      const int p = pos + __popcll(m & ((1ull << lane) - 1ull));
      const float2 w2v = wts[t];
      tok_list[p] = t;
      wt_list[p] = (k2.x == e) ? w2v.x : -w2v.y;  // sign = combine slot
    }
    pos += __popcll(m);
  }
  const int pc = (cnt + 127) & ~127;  // pad slots: token 0, weight 0
  for (int s = cnt + lane; s < pc; s += 64) {
    tok_list[offs[e] + s] = 0;
    wt_list[offs[e] + s] = 0.f;
  }
  // probs reduction: wave e sums probs[:, e] (deterministic order)
  float racc = 0.f;
  for (int t = lane; t < TT; t += 64) racc += probs[(size_t)t * EE + e];
#pragma unroll
  for (int off = 32; off > 0; off >>= 1) racc += __shfl_xor(racc, off, 64);
  if (lane == 0) {
    const float m = racc * (1.f / TT);
    sm[e] = m;
    tail[1 + e] = m;
  }
  __syncthreads();
  if (threadIdx.x == 0) {
    float loss = 0.f;
#pragma unroll
    for (int f = 0; f < EE; ++f) loss += sm[f] * sm[f];
    tail[0] = (float)EE * loss;
  }
}

// ---------------- grouped GEMM body: m97 structure (verified r7/r9/r11) ----------------
// 128x128 tile, 4 waves, BK=64, single 32KB LDS (caller-provided), gll staging.
// BOTH modes mt-fastest + XCD-chunk swizzle: consecutive blocks in an XCD share the
// same B panel (same expert for ~9 consecutive mt) -> 256KB panel L2-resident; each
// XCD fetches ~3.5nt x 8e x 256KB = 7MB of B once. (r18: nt-fastest MODE 0 over-fetched
// wguT 2.4x -> FETCH 160MB vs 67MB ideal. MODE 1 mt-fastest already verified r14.)
// MODE 0: A = xbf rows GATHERED via tok_list; B=wguT; epilogue silu(g)*u -> act bf16.
// MODE 1: A=act, B=wdT; epilogue part[slot][tok] = bf16(y*|wt|), slot=sign(wt).
template <int MODE>
static __device__ __forceinline__ void gemm_body(
    unsigned short* As, unsigned short* Bs, int bid, int nwg,
    const unsigned short* __restrict__ Ab, const unsigned short* __restrict__ Bb,
    const int* __restrict__ tab, const int* __restrict__ tok_list,
    const float* __restrict__ wt_list, unsigned short* __restrict__ dst) {
  constexpr int K   = (MODE == 0) ? DD : HH;     // 1024 / 1792
  constexpr int NBR = (MODE == 0) ? 2 * HH : DD; // B rows per expert

  const int wgid = (bid & 7) * (nwg >> 3) + (bid >> 3);  // XCD-chunk swizzle
  const int mt = wgid % MT128, nt = wgid / MT128;        // mt-fastest (both modes)
  const int e = tab[2 * mt];
  if (e < 0) return;
  const int row0 = tab[2 * mt + 1];
  const int n0 = nt * 128;

  const int tid = threadIdx.x, lane = tid & 63, wave = tid >> 6;
  const int wm = (wave >> 1) * 64, wn = (wave & 1) * 64;
  const int fr = lane & 15, hi = lane >> 4;

  const unsigned short* Bt = Bb + ((size_t)e * NBR + n0) * K;

  // staging: pass q covers LDS bytes [q*4096, q*4096+4096), rows q*32+srow0
  const int srel = tid * 16;
  const int srow0 = srel >> 7;
  const int sch = (srel >> 4) & 7;

  // A source pointers (K-invariant): MODE 0 gathers through tok_list, MODE 1 linear
  const unsigned short* srcA[4];
#pragma unroll
  for (int q = 0; q < 4; ++q) {
    const int row = q * 32 + srow0;
    const int swz = (sch ^ (row & 7)) << 3;
    if constexpr (MODE == 0)
      srcA[q] = Ab + (size_t)tok_list[row0 + row] * DD + swz;
    else
      srcA[q] = Ab + (size_t)(row0 + row) * K + swz;
  }

  f32x4 acc[4][4];
#pragma unroll
  for (int i = 0; i < 4; ++i)
#pragma unroll
    for (int j = 0; j < 4; ++j) acc[i][j] = (f32x4){0.f, 0.f, 0.f, 0.f};

  for (int k0 = 0; k0 < K; k0 += 64) {
#pragma unroll
    for (int q = 0; q < 4; ++q)  // A tile: 16KB
      gll16(srcA[q] + k0, (const char*)As + q * 4096 + srel);
#pragma unroll
    for (int q = 0; q < 4; ++q) {  // B tile: 16KB
      const int row = q * 32 + srow0;
      gll16(Bt + (size_t)row * K + k0 + ((sch ^ (row & 7)) << 3),
            (const char*)Bs + q * 4096 + srel);
    }
    __syncthreads();  // compiler drains vmcnt+lgkmcnt
#pragma unroll
    for (int kc = 0; kc < 2; ++kc) {
      short8 a[4], b[4];
#pragma unroll
      for (int i = 0; i < 4; ++i) {
        const int row = wm + i * 16 + fr;
        a[i] = *(const short8*)((const char*)As + ((row * 128 + kc * 64 + hi * 16) ^ ((row & 7) << 4)));
      }
#pragma unroll
      for (int j = 0; j < 4; ++j) {
        const int row = wn + j * 16 + fr;
        b[j] = *(const short8*)((const char*)Bs + ((row * 128 + kc * 64 + hi * 16) ^ ((row & 7) << 4)));
      }
#pragma unroll
      for (int i = 0; i < 4; ++i)
#pragma unroll
        for (int j = 0; j < 4; ++j)
          acc[i][j] = __builtin_amdgcn_mfma_f32_16x16x32_bf16(a[i], b[j], acc[i][j], 0, 0, 0);
    }
    __syncthreads();
  }

  const int r4 = hi * 4;
  if constexpr (MODE == 0) {
#pragma unroll
    for (int i = 0; i < 4; ++i)
#pragma unroll
      for (int r = 0; r < 4; ++r) {
        const int row = row0 + wm + i * 16 + r4 + r;
#pragma unroll
        for (int jj = 0; jj < 2; ++jj) {
          const float g = acc[i][2 * jj][r], u = acc[i][2 * jj + 1][r];
          const int nb = n0 + wn + jj * 32;
          const int h = ((nb >> 5) << 4) + fr;   // de-interleave to real H col
          dst[(size_t)row * HH + h] = f2bf((g / (1.f + expf(-g))) * u);
        }
      }
  } else {
#pragma unroll
    for (int i = 0; i < 4; ++i)
#pragma unroll
      for (int r = 0; r < 4; ++r) {
        const int rl = row0 + wm + i * 16 + r4 + r;
        const int tok = tok_list[rl];
        const float ws = wt_list[rl];
        if (ws != 0.f) {  // pad rows (wt==0) skipped; real weights never exactly 0
          const int slot = (ws < 0.f) ? 1 : 0;
          const float wt = fabsf(ws);
          unsigned short* prow = dst + (size_t)slot * TT * DD + (size_t)tok * DD;
#pragma unroll
          for (int j = 0; j < 4; ++j)
            prow[n0 + wn + j * 16 + fr] = f2bf(acc[i][j][r] * wt);
        }
      }
  }
}

// ------------ kernel B: gemm_gu (blocks 0..2239) + w_down prep tiles (2240..5823) ------------
// gemm_gu is compute/barrier-bound; the memory-only prep tiles fill spare CU slots +
// bandwidth (m114 co-schedule). wdT not read until gemm_dn.
__global__ __launch_bounds__(256, 3) void gemm_gu_pd(
    const unsigned short* __restrict__ Ab, const unsigned short* __restrict__ Bb,
    const int* __restrict__ tab, const int* __restrict__ tok_list,
    unsigned short* __restrict__ act,
    const float* __restrict__ w_down, unsigned short* __restrict__ wdT) {
  __shared__ char smem[32768] __attribute__((aligned(16)));
  const int bid = blockIdx.x;
  if (bid < GU_GRID) {
    gemm_body<0>((unsigned short*)smem, (unsigned short*)(smem + 16384),
                 bid, GU_GRID, Ab, Bb, tab, tok_list, nullptr, act);
  } else {
    prep_dn_tile((float(*)[65])smem, bid - GU_GRID, w_down, wdT, threadIdx.x);
  }
}

__global__ __launch_bounds__(256, 3) void gemm_dn(
    const unsigned short* __restrict__ Ab, const unsigned short* __restrict__ Bb,
    const int* __restrict__ tab, const int* __restrict__ tok_list,
    const float* __restrict__ wt_list, unsigned short* __restrict__ part) {
  __shared__ char smem[32768] __attribute__((aligned(16)));
  gemm_body<1>((unsigned short*)smem, (unsigned short*)(smem + 16384),
               blockIdx.x, gridDim.x, Ab, Bb, tab, tok_list, wt_list, part);
}

// ---------------- combine: out = part[0] + part[1] (bf16 -> f32), covers all TT*DD ------
__global__ __launch_bounds__(256) void combine_kernel(
    const unsigned short* __restrict__ part, float* __restrict__ out) {
  const size_t i = ((size_t)blockIdx.x * 256 + threadIdx.x) * 8;
  const short8 p0 = *(const short8*)(part + i);
  const short8 p1 = *(const short8*)(part + (size_t)TT * DD + i);
  f32x4 o0, o1;
#pragma unroll
  for (int j = 0; j < 4; ++j) {
    o0[j] = bf2f((unsigned short)p0[j]) + bf2f((unsigned short)p1[j]);
    o1[j] = bf2f((unsigned short)p0[4 + j]) + bf2f((unsigned short)p1[4 + j]);
  }
  *(f32x4*)(out + i) = o0;
  *(f32x4*)(out + i + 4) = o1;
}

extern "C" void kernel_launch(void* const* d_in, const int* in_sizes, int n_in,
                              void* d_out, int out_size, void* d_ws, size_t ws_size,
                              hipStream_t stream) {
  const float* x      = (const float*)d_in[0];
  const float* gw     = (const float*)d_in[1];
  const float* w_gate = (const float*)d_in[2];
  const float* w_up   = (const float*)d_in[3];
  const float* w_down = (const float*)d_in[4];
  float* out = (float*)d_out;
  float* tail = out + (size_t)TT * DD;  // [loss, mean_probs x 8]

  char* w = (char*)d_ws;
  size_t o = 0;
  auto carve = [&](size_t bytes) { char* p = w + o; o += (bytes + 255) & ~255ull; return p; };
  unsigned short* wguT = (unsigned short*)carve((size_t)EE * 2 * HH * DD * 2);  // interleaved G/U
  unsigned short* wdT  = (unsigned short*)carve((size_t)EE * DD * HH * 2);
  unsigned short* xbf  = (unsigned short*)carve((size_t)TT * DD * 2);           // bf16 x
  unsigned short* act  = (unsigned short*)carve((size_t)MP * HH * 2);
  float2* wts    = (float2*)carve((size_t)TT * 8);
  float* probs   = (float*)carve((size_t)TT * EE * 4);
  int2* topk     = (int2*)carve((size_t)TT * 8);
  int* tok_list  = (int*)carve((size_t)MP * 4);
  float* wt_list = (float*)carve((size_t)MP * 4);
  int* tab128    = (int*)carve((size_t)MT128 * 8);
  // part[2][TT][DD] bf16 (16.8 MB) aliases wguT (58.7 MB) -- wguT is dead after gemm_gu.
  unsigned short* part = wguT;

  prep_gu_gate<<<8192, 256, 0, stream>>>(w_gate, w_up, wguT, x, gw, wts, probs, topk, xbf);
  route_kernel<<<1, 512, 0, stream>>>(topk, wts, probs, tok_list, wt_list, tab128, tail);

  gemm_gu_pd<<<GU_GRID + 3584, 256, 0, stream>>>(xbf, wguT, tab128, tok_list, act,
                                                 w_down, wdT);
  gemm_dn<<<MT128 * 8, 256, 0, stream>>>(act, wdT, tab128, tok_list, wt_list, part);
  combine_kernel<<<TT * DD / 2048, 256, 0, stream>>>(part, out);
}

// Round 20
// 246.538 us; speedup vs baseline: 1.1933x; 1.0209x over previous
//
#include <hip/hip_runtime.h>
#include <stdint.h>

#define TT 4096    // B*S tokens
#define DD 1024    // model dim
#define EE 8       // experts
#define HH 1792    // hidden dim
#define MP 10240   // max padded gathered rows
#define MT128 80   // max 128-row tiles: ceil((8192+8*127)/128)=72, padded
#define GU_GRID (MT128 * 28)  // 2240, %8==0
#define TILE 8192  // elems per B tile: 128 n-rows x 64 k (16KB)

typedef __attribute__((ext_vector_type(8))) short short8;    // 8 x bf16
typedef __attribute__((ext_vector_type(4))) short short4v;   // 4 x bf16
typedef __attribute__((ext_vector_type(4))) float f32x4;

static __device__ __forceinline__ unsigned short f2bf(float f) {
  union { float f; uint32_t u; } v; v.f = f;
  return (unsigned short)((v.u + 0x7fffu + ((v.u >> 16) & 1u)) >> 16);  // RNE
}
static __device__ __forceinline__ float bf2f(unsigned short h) {
  union { uint32_t u; float f; } v; v.u = ((uint32_t)h) << 16;
  return v.f;
}

// async global->LDS, 16B/lane; LDS dest wave-uniform, global SOURCE per-lane (m104)
static __device__ __forceinline__ void gll16(const void* g, const void* l) {
  __builtin_amdgcn_global_load_lds(
      (const __attribute__((address_space(1))) unsigned int*)g,
      (__attribute__((address_space(3))) unsigned int*)l, 16, 0, 0);
}

// Converted weights live in TILED layout: contiguous 16KB tiles of [128 n-rows][64 k],
// tile index (e, np, kp) -> ((e*NP + np)*KP + kp)*TILE. Tile rows are written in plain
// logical order; gemm's gll SOURCE applies the chunk permutation (read-side XOR undoes).
// wguT: NP=28 (2H/128 interleaved G/U), KP=16 (DD/64). wdT: NP=8 (DD/128), KP=28 (HH/64).

// ---- one 64x64 transpose+convert tile for w_gate/w_up -> wguT tile (e, np=by, kp=bx) ----
// Writes: 4 runs of 16 consecutive tile-rows x 128B = 4 x 2KB contiguous (r19: scattered
// 64 x 128B @2KB stride was the untested prep bottleneck axis).
static __device__ __forceinline__ void prep_gu_tile(
    float (*L0)[65], int kind, int rr, const float* __restrict__ w_gate,
    const float* __restrict__ w_up, unsigned short* __restrict__ wguT, int tid) {
  const int lr = tid >> 2, lc = (tid & 3) * 16;
  const int e = rr / 448, r = rr % 448;
  const int bx = r / 28, by = r % 28;  // bx: d-tile(16), by: h-tile(28)
  const float* src = (kind == 0 ? w_gate : w_up) +
                     (size_t)e * DD * HH + (size_t)(bx * 64 + lr) * HH + by * 64;
#pragma unroll
  for (int q = 0; q < 4; ++q) {
    const f32x4 v = *(const f32x4*)(src + lc + 4 * q);
#pragma unroll
    for (int j = 0; j < 4; ++j) L0[lr][lc + 4 * q + j] = v[j];  // L0[d_local][h_local]
  }
  __syncthreads();
  unsigned short b0[16];
#pragma unroll
  for (int q = 0; q < 16; ++q) b0[q] = f2bf(L0[lc + q][lr]);    // (d=lc+q, h=lr)
  // h = by*64+lr -> pg = (h>>4)*32 + kind*16 + (h&15); n-panel = by, local row:
  const int lrow = (lr >> 4) * 32 + kind * 16 + (lr & 15);
  unsigned short* dst = wguT + (((size_t)e * 28 + by) * 16 + bx) * TILE +
                        (size_t)lrow * 64 + lc;
  *(short8*)(dst) = *(const short8*)&b0[0];
  *(short8*)(dst + 8) = *(const short8*)&b0[8];
}

// ---- one 64x64 transpose+convert tile for w_down -> wdT tile (e, np=by>>1, kp=bx) ----
// Writes: 64 consecutive tile-rows x 128B = one 8KB contiguous run.
static __device__ __forceinline__ void prep_dn_tile(
    float (*L0)[65], int rr, const float* __restrict__ w_down,
    unsigned short* __restrict__ wdT, int tid) {
  const int lr = tid >> 2, lc = (tid & 3) * 16;
  const int e = rr / 448, r = rr % 448;
  const int bx = r / 16, by = r % 16;  // bx: h-tile(28), by: d-tile(16)
  const float* src = w_down + (size_t)e * HH * DD + (size_t)(bx * 64 + lr) * DD + by * 64;
#pragma unroll
  for (int q = 0; q < 4; ++q) {
    const f32x4 v = *(const f32x4*)(src + lc + 4 * q);
#pragma unroll
    for (int j = 0; j < 4; ++j) L0[lr][lc + 4 * q + j] = v[j];  // L0[h_local][d_local]
  }
  __syncthreads();
  unsigned short b0[16];
#pragma unroll
  for (int q = 0; q < 16; ++q) b0[q] = f2bf(L0[lc + q][lr]);    // (h=lc+q, d=lr)
  // d = by*64+lr -> n-panel = by>>1, local row = (by&1)*64 + lr; k-panel = bx
  unsigned short* dst = wdT + (((size_t)e * 8 + (by >> 1)) * 28 + bx) * TILE +
                        (size_t)((by & 1) * 64 + lr) * 64 + lc;
  *(short8*)(dst) = *(const short8*)&b0[0];
  *(short8*)(dst + 8) = *(const short8*)&b0[8];
}

// ------------ kernel A: gate/up weight tiles + gate path, ONE launch ------------
// blocks [0,3584): w_gate tiles; [3584,7168): w_up tiles; [7168,8192): gate 4 tok/block
__global__ __launch_bounds__(256) void prep_gu_gate(
    const float* __restrict__ w_gate, const float* __restrict__ w_up,
    unsigned short* __restrict__ wguT,
    const float* __restrict__ x, const float* __restrict__ gw,
    float2* __restrict__ wts, float* __restrict__ probs, int2* __restrict__ topk,
    unsigned short* __restrict__ xbf) {
  __shared__ float L0[64][65];
  const int tid = threadIdx.x;
  const int bid = blockIdx.x;
  if (bid < 7168) {
    prep_gu_tile(L0, bid / 3584, bid % 3584, w_gate, w_up, wguT, tid);
  } else {
    // ---- gate path ----
    const int lane = tid & 63;
    const int wave = tid >> 6;
    const int t = (bid - 7168) * 4 + wave;
    const float* xr = x + (size_t)t * DD;
    float acc[EE];
#pragma unroll
    for (int e = 0; e < EE; ++e) acc[e] = 0.f;
#pragma unroll
    for (int i = 0; i < DD / 256; ++i) {
      const int d = (i * 64 + lane) * 4;
      const f32x4 xv = *(const f32x4*)(xr + d);
      unsigned short us[4];
      float xb[4];
#pragma unroll
      for (int j = 0; j < 4; ++j) { us[j] = f2bf(xv[j]); xb[j] = bf2f(us[j]); }
      *(short4v*)(xbf + (size_t)t * DD + d) = *(const short4v*)us;  // folded x->bf16
#pragma unroll
      for (int e = 0; e < EE; ++e) {
        const f32x4 gv = *(const f32x4*)(gw + e * DD + d);
#pragma unroll
        for (int j = 0; j < 4; ++j) acc[e] += xb[j] * bf2f(f2bf(gv[j]));
      }
    }
#pragma unroll
    for (int e = 0; e < EE; ++e) {
#pragma unroll
      for (int off = 32; off > 0; off >>= 1)
        acc[e] += __shfl_xor(acc[e], off, 64);
    }
    if (lane == 0) {
      float lg[EE];
#pragma unroll
      for (int e = 0; e < EE; ++e) lg[e] = bf2f(f2bf(acc[e]));
      float m1 = -1e30f, m2 = -1e30f; int i1 = 0, i2 = 0;
#pragma unroll
      for (int e = 0; e < EE; ++e) {
        const float v = lg[e];
        if (v > m1) { m2 = m1; i2 = i1; m1 = v; i1 = e; }
        else if (v > m2) { m2 = v; i2 = e; }
      }
      const float e2 = expf(m2 - m1);
      const float w1 = 1.f / (1.f + e2);
      float p[EE]; float s = 0.f;
#pragma unroll
      for (int e = 0; e < EE; ++e) { p[e] = expf(lg[e] - m1); s += p[e]; }
      const float inv = 1.f / s;
#pragma unroll
      for (int e = 0; e < EE; ++e) probs[(size_t)t * EE + e] = p[e] * inv;
      wts[t] = make_float2(w1, e2 * w1);
      topk[t] = make_int2(i1, i2);
    }
  }
}

// ------- routing (pad to 128) + tile table + probs reduction + loss (one launch) -------
// wt_list sign encodes the combine slot: +w for topk[0]-match, -w for topk[1]-match.
__global__ __launch_bounds__(512) void route_kernel(
    const int2* __restrict__ topk, const float2* __restrict__ wts,
    const float* __restrict__ probs, int* __restrict__ tok_list,
    float* __restrict__ wt_list, int* __restrict__ tab128, float* __restrict__ tail) {
  const int lane = threadIdx.x & 63;
  const int e = threadIdx.x >> 6;  // one wave per expert
  __shared__ int cnts[EE], offs[EE];
  __shared__ float sm[EE];
  int cnt = 0;
  for (int i = 0; i < TT / 64; ++i) {
    const int2 k2 = topk[i * 64 + lane];
    cnt += __popcll(__ballot(k2.x == e || k2.y == e));
  }
  if (lane == 0) cnts[e] = cnt;
  __syncthreads();
  if (threadIdx.x == 0) {
    int off = 0, n128 = 0;
    for (int f = 0; f < EE; ++f) {
      offs[f] = off;
      const int pc = (cnts[f] + 127) & ~127;
      for (int j = 0; j < (pc >> 7); ++j) {
        tab128[2 * n128] = f; tab128[2 * n128 + 1] = off + 128 * j; ++n128;
      }
      off += pc;
    }
    for (; n128 < MT128; ++n128) { tab128[2 * n128] = -1; tab128[2 * n128 + 1] = 0; }
  }
  __syncthreads();
  int pos = offs[e];
  for (int i = 0; i < TT / 64; ++i) {
    const int t = i * 64 + lane;
    const int2 k2 = topk[t];
    const bool sel = (k2.x == e || k2.y == e);
    const unsigned long long m = __ballot(sel);
    if (sel) {
      const int p = pos + __popcll(m & ((1ull << lane) - 1ull));
      const float2 w2v = wts[t];
      tok_list[p] = t;
      wt_list[p] = (k2.x == e) ? w2v.x : -w2v.y;  // sign = combine slot
    }
    pos += __popcll(m);
  }
  const int pc = (cnt + 127) & ~127;  // pad slots: token 0, weight 0
  for (int s = cnt + lane; s < pc; s += 64) {
    tok_list[offs[e] + s] = 0;
    wt_list[offs[e] + s] = 0.f;
  }
  // probs reduction: wave e sums probs[:, e] (deterministic order)
  float racc = 0.f;
  for (int t = lane; t < TT; t += 64) racc += probs[(size_t)t * EE + e];
#pragma unroll
  for (int off = 32; off > 0; off >>= 1) racc += __shfl_xor(racc, off, 64);
  if (lane == 0) {
    const float m = racc * (1.f / TT);
    sm[e] = m;
    tail[1 + e] = m;
  }
  __syncthreads();
  if (threadIdx.x == 0) {
    float loss = 0.f;
#pragma unroll
    for (int f = 0; f < EE; ++f) loss += sm[f] * sm[f];
    tail[0] = (float)EE * loss;
  }
}

// ---------------- grouped GEMM body: m97 structure (verified r7/r9/r11) ----------------
// 128x128 tile, 4 waves, BK=64, single 32KB LDS (caller-provided), gll staging.
// Both modes mt-fastest + XCD-chunk swizzle (r19: +10us on gu; B panels L2-resident).
// B is in TILED layout -> each K-step's B stage reads one dense 16KB tile.
// MODE 0: A = xbf rows GATHERED via tok_list; B=wguT; epilogue silu(g)*u -> act bf16.
// MODE 1: A=act, B=wdT; epilogue part[slot][tok] = bf16(y*|wt|), slot=sign(wt).
template <int MODE>
static __device__ __forceinline__ void gemm_body(
    unsigned short* As, unsigned short* Bs, int bid, int nwg,
    const unsigned short* __restrict__ Ab, const unsigned short* __restrict__ Bb,
    const int* __restrict__ tab, const int* __restrict__ tok_list,
    const float* __restrict__ wt_list, unsigned short* __restrict__ dst) {
  constexpr int K    = (MODE == 0) ? DD : HH;    // 1024 / 1792
  constexpr int NPAN = (MODE == 0) ? 28 : 8;     // B n-panels per expert
  constexpr int KPAN = K / 64;                   // 16 / 28

  const int wgid = (bid & 7) * (nwg >> 3) + (bid >> 3);  // XCD-chunk swizzle
  const int mt = wgid % MT128, nt = wgid / MT128;        // mt-fastest (both modes)
  const int e = tab[2 * mt];
  if (e < 0) return;
  const int row0 = tab[2 * mt + 1];
  const int n0 = nt * 128;

  const int tid = threadIdx.x, lane = tid & 63, wave = tid >> 6;
  const int wm = (wave >> 1) * 64, wn = (wave & 1) * 64;
  const int fr = lane & 15, hi = lane >> 4;

  const unsigned short* Bt0 = Bb + ((size_t)(e * NPAN + nt) * KPAN) * TILE;

  // staging: pass q covers LDS bytes [q*4096, q*4096+4096), rows q*32+srow0
  const int srel = tid * 16;
  const int srow0 = srel >> 7;
  const int sch = (srel >> 4) & 7;

  // A source pointers (K-invariant): MODE 0 gathers through tok_list, MODE 1 linear
  const unsigned short* srcA[4];
#pragma unroll
  for (int q = 0; q < 4; ++q) {
    const int row = q * 32 + srow0;
    const int swz = (sch ^ (row & 7)) << 3;
    if constexpr (MODE == 0)
      srcA[q] = Ab + (size_t)tok_list[row0 + row] * DD + swz;
    else
      srcA[q] = Ab + (size_t)(row0 + row) * K + swz;
  }
  // B source (K-invariant part): tile-local offset for this thread's rows
  int boff[4];
#pragma unroll
  for (int q = 0; q < 4; ++q) {
    const int row = q * 32 + srow0;
    boff[q] = row * 64 + ((sch ^ (row & 7)) << 3);
  }

  f32x4 acc[4][4];
#pragma unroll
  for (int i = 0; i < 4; ++i)
#pragma unroll
    for (int j = 0; j < 4; ++j) acc[i][j] = (f32x4){0.f, 0.f, 0.f, 0.f};

  for (int k0 = 0; k0 < K; k0 += 64) {
    const unsigned short* Bt = Bt0 + (k0 >> 6) * TILE;  // dense 16KB tile per K-step
#pragma unroll
    for (int q = 0; q < 4; ++q)  // A tile: 16KB
      gll16(srcA[q] + k0, (const char*)As + q * 4096 + srel);
#pragma unroll
    for (int q = 0; q < 4; ++q)  // B tile: 16KB contiguous
      gll16(Bt + boff[q], (const char*)Bs + q * 4096 + srel);
    __syncthreads();  // compiler drains vmcnt+lgkmcnt
#pragma unroll
    for (int kc = 0; kc < 2; ++kc) {
      short8 a[4], b[4];
#pragma unroll
      for (int i = 0; i < 4; ++i) {
        const int row = wm + i * 16 + fr;
        a[i] = *(const short8*)((const char*)As + ((row * 128 + kc * 64 + hi * 16) ^ ((row & 7) << 4)));
      }
#pragma unroll
      for (int j = 0; j < 4; ++j) {
        const int row = wn + j * 16 + fr;
        b[j] = *(const short8*)((const char*)Bs + ((row * 128 + kc * 64 + hi * 16) ^ ((row & 7) << 4)));
      }
#pragma unroll
      for (int i = 0; i < 4; ++i)
#pragma unroll
        for (int j = 0; j < 4; ++j)
          acc[i][j] = __builtin_amdgcn_mfma_f32_16x16x32_bf16(a[i], b[j], acc[i][j], 0, 0, 0);
    }
    __syncthreads();
  }

  const int r4 = hi * 4;
  if constexpr (MODE == 0) {
#pragma unroll
    for (int i = 0; i < 4; ++i)
#pragma unroll
      for (int r = 0; r < 4; ++r) {
        const int row = row0 + wm + i * 16 + r4 + r;
#pragma unroll
        for (int jj = 0; jj < 2; ++jj) {
          const float g = acc[i][2 * jj][r], u = acc[i][2 * jj + 1][r];
          const int nb = n0 + wn + jj * 32;
          const int h = ((nb >> 5) << 4) + fr;   // de-interleave to real H col
          dst[(size_t)row * HH + h] = f2bf((g / (1.f + expf(-g))) * u);
        }
      }
  } else {
#pragma unroll
    for (int i = 0; i < 4; ++i)
#pragma unroll
      for (int r = 0; r < 4; ++r) {
        const int rl = row0 + wm + i * 16 + r4 + r;
        const int tok = tok_list[rl];
        const float ws = wt_list[rl];
        if (ws != 0.f) {  // pad rows (wt==0) skipped; real weights never exactly 0
          const int slot = (ws < 0.f) ? 1 : 0;
          const float wt = fabsf(ws);
          unsigned short* prow = dst + (size_t)slot * TT * DD + (size_t)tok * DD;
#pragma unroll
          for (int j = 0; j < 4; ++j)
            prow[n0 + wn + j * 16 + fr] = f2bf(acc[i][j][r] * wt);
        }
      }
  }
}

// ------------ kernel B: gemm_gu (blocks 0..2239) + w_down prep tiles (2240..5823) ------------
// gemm_gu is compute/barrier-bound; the memory-only prep tiles fill spare CU slots +
// bandwidth (m114 co-schedule; r19: absorbed ~free). wdT not read until gemm_dn.
__global__ __launch_bounds__(256, 3) void gemm_gu_pd(
    const unsigned short* __restrict__ Ab, const unsigned short* __restrict__ Bb,
    const int* __restrict__ tab, const int* __restrict__ tok_list,
    unsigned short* __restrict__ act,
    const float* __restrict__ w_down, unsigned short* __restrict__ wdT) {
  __shared__ char smem[32768] __attribute__((aligned(16)));
  const int bid = blockIdx.x;
  if (bid < GU_GRID) {
    gemm_body<0>((unsigned short*)smem, (unsigned short*)(smem + 16384),
                 bid, GU_GRID, Ab, Bb, tab, tok_list, nullptr, act);
  } else {
    prep_dn_tile((float(*)[65])smem, bid - GU_GRID, w_down, wdT, threadIdx.x);
  }
}

__global__ __launch_bounds__(256, 3) void gemm_dn(
    const unsigned short* __restrict__ Ab, const unsigned short* __restrict__ Bb,
    const int* __restrict__ tab, const int* __restrict__ tok_list,
    const float* __restrict__ wt_list, unsigned short* __restrict__ part) {
  __shared__ char smem[32768] __attribute__((aligned(16)));
  gemm_body<1>((unsigned short*)smem, (unsigned short*)(smem + 16384),
               blockIdx.x, gridDim.x, Ab, Bb, tab, tok_list, wt_list, part);
}

// ---------------- combine: out = part[0] + part[1] (bf16 -> f32), covers all TT*DD ------
__global__ __launch_bounds__(256) void combine_kernel(
    const unsigned short* __restrict__ part, float* __restrict__ out) {
  const size_t i = ((size_t)blockIdx.x * 256 + threadIdx.x) * 8;
  const short8 p0 = *(const short8*)(part + i);
  const short8 p1 = *(const short8*)(part + (size_t)TT * DD + i);
  f32x4 o0, o1;
#pragma unroll
  for (int j = 0; j < 4; ++j) {
    o0[j] = bf2f((unsigned short)p0[j]) + bf2f((unsigned short)p1[j]);
    o1[j] = bf2f((unsigned short)p0[4 + j]) + bf2f((unsigned short)p1[4 + j]);
  }
  *(f32x4*)(out + i) = o0;
  *(f32x4*)(out + i + 4) = o1;
}

extern "C" void kernel_launch(void* const* d_in, const int* in_sizes, int n_in,
                              void* d_out, int out_size, void* d_ws, size_t ws_size,
                              hipStream_t stream) {
  const float* x      = (const float*)d_in[0];
  const float* gw     = (const float*)d_in[1];
  const float* w_gate = (const float*)d_in[2];
  const float* w_up   = (const float*)d_in[3];
  const float* w_down = (const float*)d_in[4];
  float* out = (float*)d_out;
  float* tail = out + (size_t)TT * DD;  // [loss, mean_probs x 8]

  char* w = (char*)d_ws;
  size_t o = 0;
  auto carve = [&](size_t bytes) { char* p = w + o; o += (bytes + 255) & ~255ull; return p; };
  unsigned short* wguT = (unsigned short*)carve((size_t)EE * 2 * HH * DD * 2);  // tiled G/U
  unsigned short* wdT  = (unsigned short*)carve((size_t)EE * DD * HH * 2);      // tiled down
  unsigned short* xbf  = (unsigned short*)carve((size_t)TT * DD * 2);           // bf16 x
  unsigned short* act  = (unsigned short*)carve((size_t)MP * HH * 2);
  float2* wts    = (float2*)carve((size_t)TT * 8);
  float* probs   = (float*)carve((size_t)TT * EE * 4);
  int2* topk     = (int2*)carve((size_t)TT * 8);
  int* tok_list  = (int*)carve((size_t)MP * 4);
  float* wt_list = (float*)carve((size_t)MP * 4);
  int* tab128    = (int*)carve((size_t)MT128 * 8);
  // part[2][TT][DD] bf16 (16.8 MB) aliases wguT (58.7 MB) -- wguT is dead after gemm_gu.
  unsigned short* part = wguT;

  prep_gu_gate<<<8192, 256, 0, stream>>>(w_gate, w_up, wguT, x, gw, wts, probs, topk, xbf);
  route_kernel<<<1, 512, 0, stream>>>(topk, wts, probs, tok_list, wt_list, tab128, tail);

  gemm_gu_pd<<<GU_GRID + 3584, 256, 0, stream>>>(xbf, wguT, tab128, tok_list, act,
                                                 w_down, wdT);
  gemm_dn<<<MT128 * 8, 256, 0, stream>>>(act, wdT, tab128, tok_list, wt_list, part);
  combine_kernel<<<TT * DD / 2048, 256, 0, stream>>>(part, out);
}